// Round 4
// baseline (4538.692 us; speedup 1.0000x reference)
//
#include <hip/hip_runtime.h>

#define NN   4096          // total nodes
#define EPN  63            // edges per node
#define ETOT (NN * EPN)    // 258048
#define NLAYER 6

__device__ __forceinline__ float silu(float x) { return x / (1.f + __expf(-x)); }

// ---------------------------------------------------------------------------
// h0 = MLP3(concat(atom_types[n], z[n/64]))   : [144] -> 256 -> 128 -> 128
// ---------------------------------------------------------------------------
__global__ __launch_bounds__(256) void k_init_h(
    const float* __restrict__ z, const float* __restrict__ at,
    const float* __restrict__ w1, const float* __restrict__ b1,
    const float* __restrict__ w2, const float* __restrict__ b2,
    const float* __restrict__ w3, const float* __restrict__ b3,
    float* __restrict__ h)
{
    __shared__ float feat[144];
    __shared__ float t1[256];
    __shared__ float t2[128];
    const int n = blockIdx.x, t = threadIdx.x;
    if (t < 16)        feat[t] = at[n * 16 + t];
    else if (t < 144)  feat[t] = z[(n >> 6) * 128 + (t - 16)];
    __syncthreads();

    float a = b1[t];
    #pragma unroll 4
    for (int k = 0; k < 144; ++k) a += feat[k] * w1[k * 256 + t];
    t1[t] = silu(a);
    __syncthreads();

    if (t < 128) {
        float a2 = b2[t];
        #pragma unroll 4
        for (int k = 0; k < 256; ++k) a2 += t1[k] * w2[k * 128 + t];
        t2[t] = silu(a2);
    }
    __syncthreads();

    if (t < 128) {
        float a3 = b3[t];
        #pragma unroll 4
        for (int k = 0; k < 128; ++k) a3 += t2[k] * w3[k * 128 + t];
        h[n * 128 + t] = a3;
    }
}

// ---------------------------------------------------------------------------
// P[n][j] = eb1[j] + sum_k h[n][k]*ew1[k][j]        (j = 0..255)
// Q[n][j] =          sum_k h[n][k]*ew1[128+k][j]
// ---------------------------------------------------------------------------
__global__ __launch_bounds__(256) void k_pq(
    const float* __restrict__ h, const float* __restrict__ ew1,
    const float* __restrict__ eb1, float* __restrict__ P, float* __restrict__ Q)
{
    __shared__ float hh[128];
    const int n = blockIdx.x, j = threadIdx.x;
    if (j < 128) hh[j] = h[n * 128 + j];
    __syncthreads();
    float p = eb1[j], q = 0.f;
    #pragma unroll 4
    for (int k = 0; k < 128; ++k) {
        float hv = hh[k];
        p += hv * ew1[k * 256 + j];
        q += hv * ew1[(128 + k) * 256 + j];
    }
    P[(size_t)n * 256 + j] = p;
    Q[(size_t)n * 256 + j] = q;
}

// ---------------------------------------------------------------------------
// Edge stage: one block per node (63 edges, all sharing row==n).
// 4 waves; each wave processes 2 groups of 8 edges; each half-wave owns
// 4 edges and a float4 column-quad (q4 = 4*(lane&31)) -> every float4
// weight load feeds 16 FMAs (2x the previous amortization; L1-BW relief).
// One per-wave LDS buffer T[8][256] is phase-aliased:
//   phase 1: t1[e][0..255]   phase 2: t2 -> T[e][0..127]
//   phase 3: msg -> T[e][128..255]
// Safe under wave-lockstep; wave_barrier() fences compiler reordering.
// agg + coord deltas accumulate in registers (no atomics).
// ---------------------------------------------------------------------------
__global__ __launch_bounds__(256) void k_edge(
    const int* __restrict__ eidx, const float* __restrict__ cin, float* __restrict__ cout,
    const float* __restrict__ P, const float* __restrict__ Q,
    const float* __restrict__ w1r,                       // ew1 row 256 (d2 weights) [256]
    const float* __restrict__ ew2, const float* __restrict__ eb2,   // [256,128],[128]
    const float* __restrict__ ew3, const float* __restrict__ eb3,   // [128,128],[128]
    const float* __restrict__ cw1, const float* __restrict__ cb1,   // [128,128],[128]
    const float* __restrict__ cw2,                                   // [128]
    float* __restrict__ agg)                                         // [N,128]
{
    __shared__ float Prow[256], w1rs[256];
    __shared__ float T[4][8][256];          // 32 KB: per-wave aliased staging
    __shared__ float aggs[4][2][128];
    __shared__ float caccs[4][2][3];

    const int n    = blockIdx.x;
    const int t    = threadIdx.x;
    const int w    = t >> 6;
    const int lane = t & 63;
    const int sub  = lane >> 5;
    const int l32  = lane & 31;
    const int q4   = l32 * 4;

    const int row = eidx[n * EPN];           // all 63 edges of this block share row
    Prow[t] = P[(size_t)row * 256 + t];
    w1rs[t] = w1r[t];
    const float crx = cin[row * 3 + 0], cry = cin[row * 3 + 1], crz = cin[row * 3 + 2];

    // hoisted per-lane column-quad constants
    const float b20 = eb2[q4], b21 = eb2[q4 + 1], b22 = eb2[q4 + 2], b23 = eb2[q4 + 3];
    const float b30 = eb3[q4], b31 = eb3[q4 + 1], b32 = eb3[q4 + 2], b33 = eb3[q4 + 3];
    const float bc0 = cb1[q4], bc1 = cb1[q4 + 1], bc2 = cb1[q4 + 2], bc3 = cb1[q4 + 3];
    const float wc0 = cw2[q4], wc1 = cw2[q4 + 1], wc2 = cw2[q4 + 2], wc3 = cw2[q4 + 3];
    __syncthreads();

    float agg0 = 0.f, agg1 = 0.f, agg2 = 0.f, agg3 = 0.f;
    float cax = 0.f, cay = 0.f, caz = 0.f;
    const int* __restrict__ colp = eidx + ETOT;

    for (int g = w; g < 8; g += 4) {
        // ---- per-half-wave edge quad (uniform across the 32 lanes) ----
        int   c[4]; bool v[4];
        float rx[4], ry[4], rz[4], d2[4];
        #pragma unroll
        for (int j = 0; j < 4; ++j) {
            const int el = 8 * g + 4 * sub + j;
            v[j] = el < EPN;
            c[j] = colp[n * EPN + (v[j] ? el : 0)];
            rx[j] = crx - cin[c[j] * 3 + 0];
            ry[j] = cry - cin[c[j] * 3 + 1];
            rz[j] = crz - cin[c[j] * 3 + 2];
            d2[j] = rx[j] * rx[j] + ry[j] * ry[j] + rz[j] * rz[j];
        }

        // ---- phase 1: t1[e] = silu(P[row] + Q[col_e] + d2_e * w1r) ----
        const float* __restrict__ Q0 = Q + (size_t)c[0] * 256;
        const float* __restrict__ Q1 = Q + (size_t)c[1] * 256;
        const float* __restrict__ Q2 = Q + (size_t)c[2] * 256;
        const float* __restrict__ Q3 = Q + (size_t)c[3] * 256;
        #pragma unroll
        for (int r = 0; r < 8; ++r) {
            const int jj = r * 32 + l32;
            const float pj = Prow[jj], wj = w1rs[jj];
            T[w][4 * sub + 0][jj] = silu(pj + Q0[jj] + d2[0] * wj);
            T[w][4 * sub + 1][jj] = silu(pj + Q1[jj] + d2[1] * wj);
            T[w][4 * sub + 2][jj] = silu(pj + Q2[jj] + d2[2] * wj);
            T[w][4 * sub + 3][jj] = silu(pj + Q3[jj] + d2[3] * wj);
        }
        __builtin_amdgcn_wave_barrier();

        // ---- phase 2: t2 = silu(t1 @ ew2 + eb2), acc in regs ----
        float a0[4] = {b20, b21, b22, b23};
        float a1[4] = {b20, b21, b22, b23};
        float a2[4] = {b20, b21, b22, b23};
        float a3[4] = {b20, b21, b22, b23};
        #pragma unroll 4
        for (int k = 0; k < 256; ++k) {
            const float4 wv = *(const float4*)(ew2 + k * 128 + q4);
            const float t0 = T[w][4 * sub + 0][k];
            const float t1v = T[w][4 * sub + 1][k];
            const float t2v = T[w][4 * sub + 2][k];
            const float t3 = T[w][4 * sub + 3][k];
            a0[0] += t0 * wv.x; a0[1] += t0 * wv.y; a0[2] += t0 * wv.z; a0[3] += t0 * wv.w;
            a1[0] += t1v * wv.x; a1[1] += t1v * wv.y; a1[2] += t1v * wv.z; a1[3] += t1v * wv.w;
            a2[0] += t2v * wv.x; a2[1] += t2v * wv.y; a2[2] += t2v * wv.z; a2[3] += t2v * wv.w;
            a3[0] += t3 * wv.x; a3[1] += t3 * wv.y; a3[2] += t3 * wv.z; a3[3] += t3 * wv.w;
        }
        __builtin_amdgcn_wave_barrier();
        // write t2 back into T[e][0..127] (t1 fully consumed; wave-lockstep safe)
        #pragma unroll
        for (int cc = 0; cc < 4; ++cc) {
            T[w][4 * sub + 0][q4 + cc] = silu(a0[cc]);
            T[w][4 * sub + 1][q4 + cc] = silu(a1[cc]);
            T[w][4 * sub + 2][q4 + cc] = silu(a2[cc]);
            T[w][4 * sub + 3][q4 + cc] = silu(a3[cc]);
        }
        __builtin_amdgcn_wave_barrier();

        // ---- phase 3: msg = t2 @ ew3 + eb3 (no activation) ----
        float m0[4] = {b30, b31, b32, b33};
        float m1[4] = {b30, b31, b32, b33};
        float m2[4] = {b30, b31, b32, b33};
        float m3[4] = {b30, b31, b32, b33};
        #pragma unroll 4
        for (int k = 0; k < 128; ++k) {
            const float4 wv = *(const float4*)(ew3 + k * 128 + q4);
            const float t0 = T[w][4 * sub + 0][k];
            const float t1v = T[w][4 * sub + 1][k];
            const float t2v = T[w][4 * sub + 2][k];
            const float t3 = T[w][4 * sub + 3][k];
            m0[0] += t0 * wv.x; m0[1] += t0 * wv.y; m0[2] += t0 * wv.z; m0[3] += t0 * wv.w;
            m1[0] += t1v * wv.x; m1[1] += t1v * wv.y; m1[2] += t1v * wv.z; m1[3] += t1v * wv.w;
            m2[0] += t2v * wv.x; m2[1] += t2v * wv.y; m2[2] += t2v * wv.z; m2[3] += t2v * wv.w;
            m3[0] += t3 * wv.x; m3[1] += t3 * wv.y; m3[2] += t3 * wv.z; m3[3] += t3 * wv.w;
        }
        // agg accumulation (register, masked)
        if (v[0]) { agg0 += m0[0]; agg1 += m0[1]; agg2 += m0[2]; agg3 += m0[3]; }
        if (v[1]) { agg0 += m1[0]; agg1 += m1[1]; agg2 += m1[2]; agg3 += m1[3]; }
        if (v[2]) { agg0 += m2[0]; agg1 += m2[1]; agg2 += m2[2]; agg3 += m2[3]; }
        if (v[3]) { agg0 += m3[0]; agg1 += m3[1]; agg2 += m3[2]; agg3 += m3[3]; }
        __builtin_amdgcn_wave_barrier();
        // write msg into T[e][128..255] (does not overlap t2 region [0..127])
        #pragma unroll
        for (int cc = 0; cc < 4; ++cc) {
            T[w][4 * sub + 0][128 + q4 + cc] = m0[cc];
            T[w][4 * sub + 1][128 + q4 + cc] = m1[cc];
            T[w][4 * sub + 2][128 + q4 + cc] = m2[cc];
            T[w][4 * sub + 3][128 + q4 + cc] = m3[cc];
        }
        __builtin_amdgcn_wave_barrier();

        // ---- phase 4: cw = silu(msg @ cw1 + cb1) @ cw2 ----
        float u0[4] = {bc0, bc1, bc2, bc3};
        float u1[4] = {bc0, bc1, bc2, bc3};
        float u2[4] = {bc0, bc1, bc2, bc3};
        float u3[4] = {bc0, bc1, bc2, bc3};
        #pragma unroll 4
        for (int k = 0; k < 128; ++k) {
            const float4 wv = *(const float4*)(cw1 + k * 128 + q4);
            const float t0 = T[w][4 * sub + 0][128 + k];
            const float t1v = T[w][4 * sub + 1][128 + k];
            const float t2v = T[w][4 * sub + 2][128 + k];
            const float t3 = T[w][4 * sub + 3][128 + k];
            u0[0] += t0 * wv.x; u0[1] += t0 * wv.y; u0[2] += t0 * wv.z; u0[3] += t0 * wv.w;
            u1[0] += t1v * wv.x; u1[1] += t1v * wv.y; u1[2] += t1v * wv.z; u1[3] += t1v * wv.w;
            u2[0] += t2v * wv.x; u2[1] += t2v * wv.y; u2[2] += t2v * wv.z; u2[3] += t2v * wv.w;
            u3[0] += t3 * wv.x; u3[1] += t3 * wv.y; u3[2] += t3 * wv.z; u3[3] += t3 * wv.w;
        }
        float p0 = silu(u0[0]) * wc0 + silu(u0[1]) * wc1 + silu(u0[2]) * wc2 + silu(u0[3]) * wc3;
        float p1 = silu(u1[0]) * wc0 + silu(u1[1]) * wc1 + silu(u1[2]) * wc2 + silu(u1[3]) * wc3;
        float p2 = silu(u2[0]) * wc0 + silu(u2[1]) * wc1 + silu(u2[2]) * wc2 + silu(u2[3]) * wc3;
        float p3 = silu(u3[0]) * wc0 + silu(u3[1]) * wc1 + silu(u3[2]) * wc2 + silu(u3[3]) * wc3;
        #pragma unroll
        for (int m = 1; m < 32; m <<= 1) {
            p0 += __shfl_xor(p0, m); p1 += __shfl_xor(p1, m);
            p2 += __shfl_xor(p2, m); p3 += __shfl_xor(p3, m);
        }
        if (v[0]) { cax += p0 * rx[0]; cay += p0 * ry[0]; caz += p0 * rz[0]; }
        if (v[1]) { cax += p1 * rx[1]; cay += p1 * ry[1]; caz += p1 * rz[1]; }
        if (v[2]) { cax += p2 * rx[2]; cay += p2 * ry[2]; caz += p2 * rz[2]; }
        if (v[3]) { cax += p3 * rx[3]; cay += p3 * ry[3]; caz += p3 * rz[3]; }
    }

    aggs[w][sub][q4 + 0] = agg0; aggs[w][sub][q4 + 1] = agg1;
    aggs[w][sub][q4 + 2] = agg2; aggs[w][sub][q4 + 3] = agg3;
    if (l32 == 0) { caccs[w][sub][0] = cax; caccs[w][sub][1] = cay; caccs[w][sub][2] = caz; }
    __syncthreads();

    if (t < 128) {
        float s = 0.f;
        #pragma unroll
        for (int i = 0; i < 4; ++i) s += aggs[i][0][t] + aggs[i][1][t];
        agg[(size_t)row * 128 + t] = s;
    }
    if (t < 3) {
        float s = 0.f;
        #pragma unroll
        for (int i = 0; i < 4; ++i) s += caccs[i][0][t] + caccs[i][1][t];
        cout[row * 3 + t] = cin[row * 3 + t] + s;
    }
}

// ---------------------------------------------------------------------------
// Node stage: hu = MLP3(concat(h, agg)); h = LayerNorm(h + hu) * g + b
// ---------------------------------------------------------------------------
__global__ __launch_bounds__(256) void k_node(
    float* __restrict__ h, const float* __restrict__ agg,
    const float* __restrict__ w1, const float* __restrict__ b1,
    const float* __restrict__ w2, const float* __restrict__ b2,
    const float* __restrict__ w3, const float* __restrict__ b3,
    const float* __restrict__ g, const float* __restrict__ b)
{
    __shared__ float xin[256];
    __shared__ float t1[256];
    __shared__ float t2[128];
    __shared__ float rs1[4], rs2[4];
    const int n = blockIdx.x, t = threadIdx.x;
    const int w = t >> 6, lane = t & 63;

    if (t < 128) xin[t] = h[(size_t)n * 128 + t];
    else         xin[t] = agg[(size_t)n * 128 + (t - 128)];
    __syncthreads();

    float a = b1[t];
    #pragma unroll 4
    for (int k = 0; k < 256; ++k) a += xin[k] * w1[k * 256 + t];
    t1[t] = silu(a);
    __syncthreads();

    if (t < 128) {
        float a2 = b2[t];
        #pragma unroll 4
        for (int k = 0; k < 256; ++k) a2 += t1[k] * w2[k * 128 + t];
        t2[t] = silu(a2);
    }
    __syncthreads();

    float x = 0.f;
    if (t < 128) {
        float a3 = b3[t];
        #pragma unroll 4
        for (int k = 0; k < 128; ++k) a3 += t2[k] * w3[k * 128 + t];
        x = xin[t] + a3;
    }
    float s1 = x, s2 = x * x;
    #pragma unroll
    for (int m = 1; m < 64; m <<= 1) { s1 += __shfl_xor(s1, m); s2 += __shfl_xor(s2, m); }
    if (lane == 0) { rs1[w] = s1; rs2[w] = s2; }
    __syncthreads();
    const float S1 = rs1[0] + rs1[1] + rs1[2] + rs1[3];
    const float S2 = rs2[0] + rs2[1] + rs2[2] + rs2[3];
    const float mu = S1 * (1.f / 128.f);
    const float var = S2 * (1.f / 128.f) - mu * mu;
    const float inv = rsqrtf(var + 1e-5f);
    if (t < 128) h[(size_t)n * 128 + t] = (x - mu) * inv * g[t] + b[t];
}

__global__ void k_copy(const float* __restrict__ src, float* __restrict__ dst, int cnt)
{
    const int i = blockIdx.x * blockDim.x + threadIdx.x;
    if (i < cnt) dst[i] = src[i];
}

// ---------------------------------------------------------------------------
extern "C" void kernel_launch(void* const* d_in, const int* in_sizes, int n_in,
                              void* d_out, int out_size, void* d_ws, size_t ws_size,
                              hipStream_t stream)
{
    const int*   eidx  = (const int*)d_in[0];
    const float* z     = (const float*)d_in[1];
    const float* at    = (const float*)d_in[2];
    const float* c0    = (const float*)d_in[3];
    const float* li_w1 = (const float*)d_in[4];
    const float* li_b1 = (const float*)d_in[5];
    const float* li_w2 = (const float*)d_in[6];
    const float* li_b2 = (const float*)d_in[7];
    const float* li_w3 = (const float*)d_in[8];
    const float* li_b3 = (const float*)d_in[9];
    const float* ew1   = (const float*)d_in[10];
    const float* eb1   = (const float*)d_in[11];
    const float* ew2   = (const float*)d_in[12];
    const float* eb2   = (const float*)d_in[13];
    const float* ew3   = (const float*)d_in[14];
    const float* eb3   = (const float*)d_in[15];
    const float* nw1   = (const float*)d_in[16];
    const float* nb1   = (const float*)d_in[17];
    const float* nw2   = (const float*)d_in[18];
    const float* nb2   = (const float*)d_in[19];
    const float* nw3   = (const float*)d_in[20];
    const float* nb3   = (const float*)d_in[21];
    const float* cw1   = (const float*)d_in[22];
    const float* cb1   = (const float*)d_in[23];
    const float* cw2   = (const float*)d_in[24];
    const float* lng   = (const float*)d_in[25];
    const float* lnb   = (const float*)d_in[26];

    float* ws   = (float*)d_ws;
    float* h    = ws;                       // [4096,128]
    float* P    = h   + (size_t)NN * 128;   // [4096,256]
    float* Q    = P   + (size_t)NN * 256;   // [4096,256]
    float* agg  = Q   + (size_t)NN * 256;   // [4096,128]
    float* cbA  = agg + (size_t)NN * 128;   // [4096,3]
    float* cbB  = cbA + (size_t)NN * 3;     // [4096,3]
    float* outp = (float*)d_out;

    k_init_h<<<NN, 256, 0, stream>>>(z, at, li_w1, li_b1, li_w2, li_b2, li_w3, li_b3, h);
    k_copy<<<(NN * 3 + 255) / 256, 256, 0, stream>>>(c0, cbA, NN * 3);

    for (int l = 0; l < NLAYER; ++l) {
        const float* ew1l = ew1 + (size_t)l * 257 * 256;
        k_pq<<<NN, 256, 0, stream>>>(h, ew1l, eb1 + l * 256, P, Q);

        const float* cin = (l & 1) ? cbB : cbA;
        float* cout      = (l == NLAYER - 1) ? outp : ((l & 1) ? cbA : cbB);
        k_edge<<<NN, 256, 0, stream>>>(eidx, cin, cout, P, Q,
            ew1l + 256 * 256,
            ew2 + (size_t)l * 256 * 128, eb2 + l * 128,
            ew3 + (size_t)l * 128 * 128, eb3 + l * 128,
            cw1 + (size_t)l * 128 * 128, cb1 + l * 128,
            cw2 + (size_t)l * 128, agg);

        k_node<<<NN, 256, 0, stream>>>(h, agg,
            nw1 + (size_t)l * 256 * 256, nb1 + l * 256,
            nw2 + (size_t)l * 256 * 128, nb2 + l * 128,
            nw3 + (size_t)l * 128 * 128, nb3 + l * 128,
            lng + l * 128, lnb + l * 128);
    }
}

// Round 5
// 4041.643 us; speedup vs baseline: 1.1230x; 1.1230x over previous
//
#include <hip/hip_runtime.h>

#define NN   4096          // total nodes
#define EPN  63            // edges per node
#define ETOT (NN * EPN)    // 258048
#define NLAYER 6

__device__ __forceinline__ float silu(float x) { return x / (1.f + __expf(-x)); }

// ---------------------------------------------------------------------------
// h0 = MLP3(concat(atom_types[n], z[n/64]))   : [144] -> 256 -> 128 -> 128
// ---------------------------------------------------------------------------
__global__ __launch_bounds__(256) void k_init_h(
    const float* __restrict__ z, const float* __restrict__ at,
    const float* __restrict__ w1, const float* __restrict__ b1,
    const float* __restrict__ w2, const float* __restrict__ b2,
    const float* __restrict__ w3, const float* __restrict__ b3,
    float* __restrict__ h)
{
    __shared__ float feat[144];
    __shared__ float t1[256];
    __shared__ float t2[128];
    const int n = blockIdx.x, t = threadIdx.x;
    if (t < 16)        feat[t] = at[n * 16 + t];
    else if (t < 144)  feat[t] = z[(n >> 6) * 128 + (t - 16)];
    __syncthreads();

    float a = b1[t];
    #pragma unroll 4
    for (int k = 0; k < 144; ++k) a += feat[k] * w1[k * 256 + t];
    t1[t] = silu(a);
    __syncthreads();

    if (t < 128) {
        float a2 = b2[t];
        #pragma unroll 4
        for (int k = 0; k < 256; ++k) a2 += t1[k] * w2[k * 128 + t];
        t2[t] = silu(a2);
    }
    __syncthreads();

    if (t < 128) {
        float a3 = b3[t];
        #pragma unroll 4
        for (int k = 0; k < 128; ++k) a3 += t2[k] * w3[k * 128 + t];
        h[n * 128 + t] = a3;
    }
}

// ---------------------------------------------------------------------------
// P[n][j] = eb1[j] + sum_k h[n][k]*ew1[k][j]        (j = 0..255)
// Q[n][j] =          sum_k h[n][k]*ew1[128+k][j]
// ---------------------------------------------------------------------------
__global__ __launch_bounds__(256) void k_pq(
    const float* __restrict__ h, const float* __restrict__ ew1,
    const float* __restrict__ eb1, float* __restrict__ P, float* __restrict__ Q)
{
    __shared__ float hh[128];
    const int n = blockIdx.x, j = threadIdx.x;
    if (j < 128) hh[j] = h[n * 128 + j];
    __syncthreads();
    float p = eb1[j], q = 0.f;
    #pragma unroll 4
    for (int k = 0; k < 128; ++k) {
        float hv = hh[k];
        p += hv * ew1[k * 256 + j];
        q += hv * ew1[(128 + k) * 256 + j];
    }
    P[(size_t)n * 256 + j] = p;
    Q[(size_t)n * 256 + j] = q;
}

// ---------------------------------------------------------------------------
// Edge stage: one block per node (63 edges + 1 pad, all sharing row==n).
// 4 waves; wave w owns edges [16w, 16w+16); each half-wave owns 8 edges and
// a float4 column-quad (q4 = 4*(lane&31)) -> every float4 weight load feeds
// 32 FMAs, and each wave streams the weights exactly ONCE (single pass).
// L1 demand ~32 B/cy/CU (was ~64 = saturated). LDS-read:VALU ratio per k is
// unchanged from the measured 0-conflict kernel (b32 broadcasts).
// Per-wave LDS T[16][256] phase-aliased:
//   phase 1: t1[e][0..255]; phase 2: t2 -> T[e][0..127];
//   phase 3: msg -> T[e][128..255].
// Wave-lockstep + wave_barrier() compiler fences. No atomics anywhere.
// ---------------------------------------------------------------------------
__global__ __launch_bounds__(256) void k_edge(
    const int* __restrict__ eidx, const float* __restrict__ cin, float* __restrict__ cout,
    const float* __restrict__ P, const float* __restrict__ Q,
    const float* __restrict__ w1r,                       // ew1 row 256 (d2 weights) [256]
    const float* __restrict__ ew2, const float* __restrict__ eb2,   // [256,128],[128]
    const float* __restrict__ ew3, const float* __restrict__ eb3,   // [128,128],[128]
    const float* __restrict__ cw1, const float* __restrict__ cb1,   // [128,128],[128]
    const float* __restrict__ cw2,                                   // [128]
    float* __restrict__ agg)                                         // [N,128]
{
    __shared__ float Prow[256], w1rs[256];
    __shared__ float T[4][16][256];         // 64 KB per-wave aliased staging
    __shared__ float aggs[4][2][128];
    __shared__ float caccs[4][2][3];

    const int n    = blockIdx.x;
    const int t    = threadIdx.x;
    const int w    = t >> 6;
    const int lane = t & 63;
    const int sub  = lane >> 5;
    const int l32  = lane & 31;
    const int q4   = l32 * 4;

    const int row = eidx[n * EPN];           // all 63 edges of this block share row
    Prow[t] = P[(size_t)row * 256 + t];
    w1rs[t] = w1r[t];
    const float crx = cin[row * 3 + 0], cry = cin[row * 3 + 1], crz = cin[row * 3 + 2];

    // hoisted per-lane column-quad constants
    const float b20 = eb2[q4], b21 = eb2[q4 + 1], b22 = eb2[q4 + 2], b23 = eb2[q4 + 3];
    const float b30 = eb3[q4], b31 = eb3[q4 + 1], b32 = eb3[q4 + 2], b33 = eb3[q4 + 3];
    const float bc0 = cb1[q4], bc1 = cb1[q4 + 1], bc2 = cb1[q4 + 2], bc3 = cb1[q4 + 3];
    const float wc0 = cw2[q4], wc1 = cw2[q4 + 1], wc2 = cw2[q4 + 2], wc3 = cw2[q4 + 3];
    __syncthreads();

    float agg0 = 0.f, agg1 = 0.f, agg2 = 0.f, agg3 = 0.f;
    float cax = 0.f, cay = 0.f, caz = 0.f;
    const int* __restrict__ colp = eidx + ETOT;
    const int eb = 8 * sub;                  // this half-wave's edge base within T[w]

    // ---- per-half-wave edge octet (uniform across the 32 lanes) ----
    int   c[8]; bool v[8];
    float rx[8], ry[8], rz[8], d2[8];
    #pragma unroll
    for (int j = 0; j < 8; ++j) {
        const int el = 16 * w + 8 * sub + j;
        v[j] = el < EPN;
        c[j] = colp[n * EPN + (v[j] ? el : 0)];
        rx[j] = crx - cin[c[j] * 3 + 0];
        ry[j] = cry - cin[c[j] * 3 + 1];
        rz[j] = crz - cin[c[j] * 3 + 2];
        d2[j] = rx[j] * rx[j] + ry[j] * ry[j] + rz[j] * rz[j];
    }

    // ---- phase 1: t1[e] = silu(P[row] + Q[col_e] + d2_e * w1r) ----
    #pragma unroll
    for (int j = 0; j < 8; ++j) {
        const float* __restrict__ Qj = Q + (size_t)c[j] * 256;
        const float dd = d2[j];
        #pragma unroll
        for (int r = 0; r < 8; ++r) {
            const int jj = r * 32 + l32;
            T[w][eb + j][jj] = silu(Prow[jj] + Qj[jj] + dd * w1rs[jj]);
        }
    }
    __builtin_amdgcn_wave_barrier();

    // ---- phase 2: t2 = silu(t1 @ ew2 + eb2), acc in regs ----
    float a[8][4];
    #pragma unroll
    for (int e = 0; e < 8; ++e) { a[e][0] = b20; a[e][1] = b21; a[e][2] = b22; a[e][3] = b23; }
    #pragma unroll 2
    for (int k = 0; k < 256; ++k) {
        const float4 wv = *(const float4*)(ew2 + k * 128 + q4);
        #pragma unroll
        for (int e = 0; e < 8; ++e) {
            const float tv = T[w][eb + e][k];
            a[e][0] += tv * wv.x; a[e][1] += tv * wv.y;
            a[e][2] += tv * wv.z; a[e][3] += tv * wv.w;
        }
    }
    __builtin_amdgcn_wave_barrier();
    // write t2 into T[e][0..127] (t1 fully consumed; wave-lockstep safe)
    #pragma unroll
    for (int e = 0; e < 8; ++e) {
        T[w][eb + e][q4 + 0] = silu(a[e][0]);
        T[w][eb + e][q4 + 1] = silu(a[e][1]);
        T[w][eb + e][q4 + 2] = silu(a[e][2]);
        T[w][eb + e][q4 + 3] = silu(a[e][3]);
    }
    __builtin_amdgcn_wave_barrier();

    // ---- phase 3: msg = t2 @ ew3 + eb3 (no activation) ----
    float m[8][4];
    #pragma unroll
    for (int e = 0; e < 8; ++e) { m[e][0] = b30; m[e][1] = b31; m[e][2] = b32; m[e][3] = b33; }
    #pragma unroll 2
    for (int k = 0; k < 128; ++k) {
        const float4 wv = *(const float4*)(ew3 + k * 128 + q4);
        #pragma unroll
        for (int e = 0; e < 8; ++e) {
            const float tv = T[w][eb + e][k];
            m[e][0] += tv * wv.x; m[e][1] += tv * wv.y;
            m[e][2] += tv * wv.z; m[e][3] += tv * wv.w;
        }
    }
    #pragma unroll
    for (int e = 0; e < 8; ++e) {
        if (v[e]) { agg0 += m[e][0]; agg1 += m[e][1]; agg2 += m[e][2]; agg3 += m[e][3]; }
    }
    __builtin_amdgcn_wave_barrier();
    // write msg into T[e][128..255] (does not overlap t2 region [0..127])
    #pragma unroll
    for (int e = 0; e < 8; ++e) {
        T[w][eb + e][128 + q4 + 0] = m[e][0];
        T[w][eb + e][128 + q4 + 1] = m[e][1];
        T[w][eb + e][128 + q4 + 2] = m[e][2];
        T[w][eb + e][128 + q4 + 3] = m[e][3];
    }
    __builtin_amdgcn_wave_barrier();

    // ---- phase 4: cw = silu(msg @ cw1 + cb1) @ cw2 ----
    float u[8][4];
    #pragma unroll
    for (int e = 0; e < 8; ++e) { u[e][0] = bc0; u[e][1] = bc1; u[e][2] = bc2; u[e][3] = bc3; }
    #pragma unroll 2
    for (int k = 0; k < 128; ++k) {
        const float4 wv = *(const float4*)(cw1 + k * 128 + q4);
        #pragma unroll
        for (int e = 0; e < 8; ++e) {
            const float tv = T[w][eb + e][128 + k];
            u[e][0] += tv * wv.x; u[e][1] += tv * wv.y;
            u[e][2] += tv * wv.z; u[e][3] += tv * wv.w;
        }
    }
    float p[8];
    #pragma unroll
    for (int e = 0; e < 8; ++e)
        p[e] = silu(u[e][0]) * wc0 + silu(u[e][1]) * wc1 + silu(u[e][2]) * wc2 + silu(u[e][3]) * wc3;
    #pragma unroll
    for (int msk = 1; msk < 32; msk <<= 1) {
        #pragma unroll
        for (int e = 0; e < 8; ++e) p[e] += __shfl_xor(p[e], msk);
    }
    #pragma unroll
    for (int e = 0; e < 8; ++e) {
        if (v[e]) { cax += p[e] * rx[e]; cay += p[e] * ry[e]; caz += p[e] * rz[e]; }
    }

    aggs[w][sub][q4 + 0] = agg0; aggs[w][sub][q4 + 1] = agg1;
    aggs[w][sub][q4 + 2] = agg2; aggs[w][sub][q4 + 3] = agg3;
    if (l32 == 0) { caccs[w][sub][0] = cax; caccs[w][sub][1] = cay; caccs[w][sub][2] = caz; }
    __syncthreads();

    if (t < 128) {
        float s = 0.f;
        #pragma unroll
        for (int i = 0; i < 4; ++i) s += aggs[i][0][t] + aggs[i][1][t];
        agg[(size_t)row * 128 + t] = s;
    }
    if (t < 3) {
        float s = 0.f;
        #pragma unroll
        for (int i = 0; i < 4; ++i) s += caccs[i][0][t] + caccs[i][1][t];
        cout[row * 3 + t] = cin[row * 3 + t] + s;
    }
}

// ---------------------------------------------------------------------------
// Node stage: hu = MLP3(concat(h, agg)); h = LayerNorm(h + hu) * g + b
// ---------------------------------------------------------------------------
__global__ __launch_bounds__(256) void k_node(
    float* __restrict__ h, const float* __restrict__ agg,
    const float* __restrict__ w1, const float* __restrict__ b1,
    const float* __restrict__ w2, const float* __restrict__ b2,
    const float* __restrict__ w3, const float* __restrict__ b3,
    const float* __restrict__ g, const float* __restrict__ b)
{
    __shared__ float xin[256];
    __shared__ float t1[256];
    __shared__ float t2[128];
    __shared__ float rs1[4], rs2[4];
    const int n = blockIdx.x, t = threadIdx.x;
    const int w = t >> 6, lane = t & 63;

    if (t < 128) xin[t] = h[(size_t)n * 128 + t];
    else         xin[t] = agg[(size_t)n * 128 + (t - 128)];
    __syncthreads();

    float a = b1[t];
    #pragma unroll 4
    for (int k = 0; k < 256; ++k) a += xin[k] * w1[k * 256 + t];
    t1[t] = silu(a);
    __syncthreads();

    if (t < 128) {
        float a2 = b2[t];
        #pragma unroll 4
        for (int k = 0; k < 256; ++k) a2 += t1[k] * w2[k * 128 + t];
        t2[t] = silu(a2);
    }
    __syncthreads();

    float x = 0.f;
    if (t < 128) {
        float a3 = b3[t];
        #pragma unroll 4
        for (int k = 0; k < 128; ++k) a3 += t2[k] * w3[k * 128 + t];
        x = xin[t] + a3;
    }
    float s1 = x, s2 = x * x;
    #pragma unroll
    for (int m = 1; m < 64; m <<= 1) { s1 += __shfl_xor(s1, m); s2 += __shfl_xor(s2, m); }
    if (lane == 0) { rs1[w] = s1; rs2[w] = s2; }
    __syncthreads();
    const float S1 = rs1[0] + rs1[1] + rs1[2] + rs1[3];
    const float S2 = rs2[0] + rs2[1] + rs2[2] + rs2[3];
    const float mu = S1 * (1.f / 128.f);
    const float var = S2 * (1.f / 128.f) - mu * mu;
    const float inv = rsqrtf(var + 1e-5f);
    if (t < 128) h[(size_t)n * 128 + t] = (x - mu) * inv * g[t] + b[t];
}

__global__ void k_copy(const float* __restrict__ src, float* __restrict__ dst, int cnt)
{
    const int i = blockIdx.x * blockDim.x + threadIdx.x;
    if (i < cnt) dst[i] = src[i];
}

// ---------------------------------------------------------------------------
extern "C" void kernel_launch(void* const* d_in, const int* in_sizes, int n_in,
                              void* d_out, int out_size, void* d_ws, size_t ws_size,
                              hipStream_t stream)
{
    const int*   eidx  = (const int*)d_in[0];
    const float* z     = (const float*)d_in[1];
    const float* at    = (const float*)d_in[2];
    const float* c0    = (const float*)d_in[3];
    const float* li_w1 = (const float*)d_in[4];
    const float* li_b1 = (const float*)d_in[5];
    const float* li_w2 = (const float*)d_in[6];
    const float* li_b2 = (const float*)d_in[7];
    const float* li_w3 = (const float*)d_in[8];
    const float* li_b3 = (const float*)d_in[9];
    const float* ew1   = (const float*)d_in[10];
    const float* eb1   = (const float*)d_in[11];
    const float* ew2   = (const float*)d_in[12];
    const float* eb2   = (const float*)d_in[13];
    const float* ew3   = (const float*)d_in[14];
    const float* eb3   = (const float*)d_in[15];
    const float* nw1   = (const float*)d_in[16];
    const float* nb1   = (const float*)d_in[17];
    const float* nw2   = (const float*)d_in[18];
    const float* nb2   = (const float*)d_in[19];
    const float* nw3   = (const float*)d_in[20];
    const float* nb3   = (const float*)d_in[21];
    const float* cw1   = (const float*)d_in[22];
    const float* cb1   = (const float*)d_in[23];
    const float* cw2   = (const float*)d_in[24];
    const float* lng   = (const float*)d_in[25];
    const float* lnb   = (const float*)d_in[26];

    float* ws   = (float*)d_ws;
    float* h    = ws;                       // [4096,128]
    float* P    = h   + (size_t)NN * 128;   // [4096,256]
    float* Q    = P   + (size_t)NN * 256;   // [4096,256]
    float* agg  = Q   + (size_t)NN * 256;   // [4096,128]
    float* cbA  = agg + (size_t)NN * 128;   // [4096,3]
    float* cbB  = cbA + (size_t)NN * 3;     // [4096,3]
    float* outp = (float*)d_out;

    k_init_h<<<NN, 256, 0, stream>>>(z, at, li_w1, li_b1, li_w2, li_b2, li_w3, li_b3, h);
    k_copy<<<(NN * 3 + 255) / 256, 256, 0, stream>>>(c0, cbA, NN * 3);

    for (int l = 0; l < NLAYER; ++l) {
        const float* ew1l = ew1 + (size_t)l * 257 * 256;
        k_pq<<<NN, 256, 0, stream>>>(h, ew1l, eb1 + l * 256, P, Q);

        const float* cin = (l & 1) ? cbB : cbA;
        float* cout      = (l == NLAYER - 1) ? outp : ((l & 1) ? cbA : cbB);
        k_edge<<<NN, 256, 0, stream>>>(eidx, cin, cout, P, Q,
            ew1l + 256 * 256,
            ew2 + (size_t)l * 256 * 128, eb2 + l * 128,
            ew3 + (size_t)l * 128 * 128, eb3 + l * 128,
            cw1 + (size_t)l * 128 * 128, cb1 + l * 128,
            cw2 + (size_t)l * 128, agg);

        k_node<<<NN, 256, 0, stream>>>(h, agg,
            nw1 + (size_t)l * 256 * 256, nb1 + l * 256,
            nw2 + (size_t)l * 256 * 128, nb2 + l * 128,
            nw3 + (size_t)l * 128 * 128, nb3 + l * 128,
            lng + l * 128, lnb + l * 128);
    }
}

// Round 6
// 3725.368 us; speedup vs baseline: 1.2183x; 1.0849x over previous
//
#include <hip/hip_runtime.h>

#define NN   4096          // total nodes
#define EPN  63            // edges per node
#define ETOT (NN * EPN)    // 258048
#define NLAYER 6

__device__ __forceinline__ float silu(float x) { return x / (1.f + __expf(-x)); }

// ---------------------------------------------------------------------------
// h0 = MLP3(concat(atom_types[n], z[n/64]))   : [144] -> 256 -> 128 -> 128
// ---------------------------------------------------------------------------
__global__ __launch_bounds__(256) void k_init_h(
    const float* __restrict__ z, const float* __restrict__ at,
    const float* __restrict__ w1, const float* __restrict__ b1,
    const float* __restrict__ w2, const float* __restrict__ b2,
    const float* __restrict__ w3, const float* __restrict__ b3,
    float* __restrict__ h)
{
    __shared__ float feat[144];
    __shared__ float t1[256];
    __shared__ float t2[128];
    const int n = blockIdx.x, t = threadIdx.x;
    if (t < 16)        feat[t] = at[n * 16 + t];
    else if (t < 144)  feat[t] = z[(n >> 6) * 128 + (t - 16)];
    __syncthreads();

    float a = b1[t];
    #pragma unroll 4
    for (int k = 0; k < 144; ++k) a += feat[k] * w1[k * 256 + t];
    t1[t] = silu(a);
    __syncthreads();

    if (t < 128) {
        float a2 = b2[t];
        #pragma unroll 4
        for (int k = 0; k < 256; ++k) a2 += t1[k] * w2[k * 128 + t];
        t2[t] = silu(a2);
    }
    __syncthreads();

    if (t < 128) {
        float a3 = b3[t];
        #pragma unroll 4
        for (int k = 0; k < 128; ++k) a3 += t2[k] * w3[k * 128 + t];
        h[n * 128 + t] = a3;
    }
}

// ---------------------------------------------------------------------------
// P[n][j] = eb1[j] + sum_k h[n][k]*ew1[k][j]        (j = 0..255)
// Q[n][j] =          sum_k h[n][k]*ew1[128+k][j]
// ---------------------------------------------------------------------------
__global__ __launch_bounds__(256) void k_pq(
    const float* __restrict__ h, const float* __restrict__ ew1,
    const float* __restrict__ eb1, float* __restrict__ P, float* __restrict__ Q)
{
    __shared__ float hh[128];
    const int n = blockIdx.x, j = threadIdx.x;
    if (j < 128) hh[j] = h[n * 128 + j];
    __syncthreads();
    float p = eb1[j], q = 0.f;
    #pragma unroll 4
    for (int k = 0; k < 128; ++k) {
        float hv = hh[k];
        p += hv * ew1[k * 256 + j];
        q += hv * ew1[(128 + k) * 256 + j];
    }
    P[(size_t)n * 256 + j] = p;
    Q[(size_t)n * 256 + j] = q;
}

// ---------------------------------------------------------------------------
// Edge stage: one block per node (63 edges + 1 pad, all sharing row==n).
// 4 waves; wave w owns edges [16w,16w+16); each half-wave owns 8 edges and a
// float4 column-quad (q4) -> each float4 weight load feeds 32 FMAs, single
// weight pass per wave. t1 broadcasts batched as ds_read_b128 (4 k-steps per
// read, 4x fewer DS instrs). Staging T is [16][128] (32 KB), phase-aliased:
//   phase 1+2 run twice over 128-col k-tiles of t1;
//   then t2 -> T[e][0..127]; msg (reg-complete) -> T[e][0..127].
// Wave-lockstep + wave_barrier() compiler fences. No atomics anywhere.
// ---------------------------------------------------------------------------
__global__ __launch_bounds__(256, 3) void k_edge(
    const int* __restrict__ eidx, const float* __restrict__ cin, float* __restrict__ cout,
    const float* __restrict__ P, const float* __restrict__ Q,
    const float* __restrict__ w1r,                       // ew1 row 256 (d2 weights) [256]
    const float* __restrict__ ew2, const float* __restrict__ eb2,   // [256,128],[128]
    const float* __restrict__ ew3, const float* __restrict__ eb3,   // [128,128],[128]
    const float* __restrict__ cw1, const float* __restrict__ cb1,   // [128,128],[128]
    const float* __restrict__ cw2,                                   // [128]
    float* __restrict__ agg)                                         // [N,128]
{
    __shared__ float Prow[256], w1rs[256];
    __shared__ float T[4][16][128];         // 32 KB per-wave aliased staging
    __shared__ float aggs[4][2][128];
    __shared__ float caccs[4][2][3];

    const int n    = blockIdx.x;
    const int t    = threadIdx.x;
    const int w    = t >> 6;
    const int lane = t & 63;
    const int sub  = lane >> 5;
    const int l32  = lane & 31;
    const int q4   = l32 * 4;

    const int row = eidx[n * EPN];           // all 63 edges of this block share row
    Prow[t] = P[(size_t)row * 256 + t];
    w1rs[t] = w1r[t];
    const float crx = cin[row * 3 + 0], cry = cin[row * 3 + 1], crz = cin[row * 3 + 2];

    // hoisted per-lane column-quad constants
    const float b20 = eb2[q4], b21 = eb2[q4 + 1], b22 = eb2[q4 + 2], b23 = eb2[q4 + 3];
    const float b30 = eb3[q4], b31 = eb3[q4 + 1], b32 = eb3[q4 + 2], b33 = eb3[q4 + 3];
    const float bc0 = cb1[q4], bc1 = cb1[q4 + 1], bc2 = cb1[q4 + 2], bc3 = cb1[q4 + 3];
    const float wc0 = cw2[q4], wc1 = cw2[q4 + 1], wc2 = cw2[q4 + 2], wc3 = cw2[q4 + 3];
    __syncthreads();

    float agg0 = 0.f, agg1 = 0.f, agg2 = 0.f, agg3 = 0.f;
    float cax = 0.f, cay = 0.f, caz = 0.f;
    const int* __restrict__ colp = eidx + ETOT;
    const int eb = 8 * sub;                  // this half-wave's edge base within T[w]

    // ---- per-half-wave edge octet (uniform across the 32 lanes) ----
    int   c[8]; bool v[8];
    float rx[8], ry[8], rz[8], d2[8];
    #pragma unroll
    for (int j = 0; j < 8; ++j) {
        const int el = 16 * w + 8 * sub + j;
        v[j] = el < EPN;
        c[j] = colp[n * EPN + (v[j] ? el : 0)];
        rx[j] = crx - cin[c[j] * 3 + 0];
        ry[j] = cry - cin[c[j] * 3 + 1];
        rz[j] = crz - cin[c[j] * 3 + 2];
        d2[j] = rx[j] * rx[j] + ry[j] * ry[j] + rz[j] * rz[j];
    }

    // ---- phases 1+2 (two 128-col k-tiles): t1 tile -> LDS; partial GEMM1 ----
    float a[8][4];
    #pragma unroll
    for (int e = 0; e < 8; ++e) { a[e][0] = b20; a[e][1] = b21; a[e][2] = b22; a[e][3] = b23; }

    #pragma unroll
    for (int tile = 0; tile < 2; ++tile) {
        const int kbase = tile * 128;
        // phase 1: t1[e][kbase..kbase+128) = silu(P + Q[col] + d2*w1r)
        #pragma unroll
        for (int j = 0; j < 8; ++j) {
            const float* __restrict__ Qj = Q + (size_t)c[j] * 256 + kbase;
            const float dd = d2[j];
            #pragma unroll
            for (int r = 0; r < 4; ++r) {
                const int jj = r * 32 + l32;
                T[w][eb + j][jj] = silu(Prow[kbase + jj] + Qj[jj] + dd * w1rs[kbase + jj]);
            }
        }
        __builtin_amdgcn_wave_barrier();

        // phase 2 partial: a += t1_tile @ ew2[kbase..kbase+128)
        for (int k4 = 0; k4 < 32; ++k4) {
            float4 t1q[8];
            #pragma unroll
            for (int e = 0; e < 8; ++e)
                t1q[e] = *(const float4*)&T[w][eb + e][4 * k4];
            #pragma unroll
            for (int kk = 0; kk < 4; ++kk) {
                const float4 wv = *(const float4*)(ew2 + (size_t)(kbase + 4 * k4 + kk) * 128 + q4);
                #pragma unroll
                for (int e = 0; e < 8; ++e) {
                    const float tv = (&t1q[e].x)[kk];
                    a[e][0] += tv * wv.x; a[e][1] += tv * wv.y;
                    a[e][2] += tv * wv.z; a[e][3] += tv * wv.w;
                }
            }
        }
        __builtin_amdgcn_wave_barrier();
    }

    // write t2 into T[e][0..127] (t1 fully consumed; wave-lockstep safe)
    #pragma unroll
    for (int e = 0; e < 8; ++e) {
        T[w][eb + e][q4 + 0] = silu(a[e][0]);
        T[w][eb + e][q4 + 1] = silu(a[e][1]);
        T[w][eb + e][q4 + 2] = silu(a[e][2]);
        T[w][eb + e][q4 + 3] = silu(a[e][3]);
    }
    __builtin_amdgcn_wave_barrier();

    // ---- phase 3: msg = t2 @ ew3 + eb3 (fully reg-accumulated) ----
    float m[8][4];
    #pragma unroll
    for (int e = 0; e < 8; ++e) { m[e][0] = b30; m[e][1] = b31; m[e][2] = b32; m[e][3] = b33; }
    for (int k4 = 0; k4 < 32; ++k4) {
        float4 t2q[8];
        #pragma unroll
        for (int e = 0; e < 8; ++e)
            t2q[e] = *(const float4*)&T[w][eb + e][4 * k4];
        #pragma unroll
        for (int kk = 0; kk < 4; ++kk) {
            const float4 wv = *(const float4*)(ew3 + (size_t)(4 * k4 + kk) * 128 + q4);
            #pragma unroll
            for (int e = 0; e < 8; ++e) {
                const float tv = (&t2q[e].x)[kk];
                m[e][0] += tv * wv.x; m[e][1] += tv * wv.y;
                m[e][2] += tv * wv.z; m[e][3] += tv * wv.w;
            }
        }
    }
    #pragma unroll
    for (int e = 0; e < 8; ++e) {
        if (v[e]) { agg0 += m[e][0]; agg1 += m[e][1]; agg2 += m[e][2]; agg3 += m[e][3]; }
    }
    __builtin_amdgcn_wave_barrier();
    // overwrite t2 with msg (t2 dead after the reg-complete loop above)
    #pragma unroll
    for (int e = 0; e < 8; ++e) {
        T[w][eb + e][q4 + 0] = m[e][0];
        T[w][eb + e][q4 + 1] = m[e][1];
        T[w][eb + e][q4 + 2] = m[e][2];
        T[w][eb + e][q4 + 3] = m[e][3];
    }
    __builtin_amdgcn_wave_barrier();

    // ---- phase 4: cw = silu(msg @ cw1 + cb1) @ cw2 ----
    float u[8][4];
    #pragma unroll
    for (int e = 0; e < 8; ++e) { u[e][0] = bc0; u[e][1] = bc1; u[e][2] = bc2; u[e][3] = bc3; }
    for (int k4 = 0; k4 < 32; ++k4) {
        float4 mq[8];
        #pragma unroll
        for (int e = 0; e < 8; ++e)
            mq[e] = *(const float4*)&T[w][eb + e][4 * k4];
        #pragma unroll
        for (int kk = 0; kk < 4; ++kk) {
            const float4 wv = *(const float4*)(cw1 + (size_t)(4 * k4 + kk) * 128 + q4);
            #pragma unroll
            for (int e = 0; e < 8; ++e) {
                const float tv = (&mq[e].x)[kk];
                u[e][0] += tv * wv.x; u[e][1] += tv * wv.y;
                u[e][2] += tv * wv.z; u[e][3] += tv * wv.w;
            }
        }
    }
    float p[8];
    #pragma unroll
    for (int e = 0; e < 8; ++e)
        p[e] = silu(u[e][0]) * wc0 + silu(u[e][1]) * wc1 + silu(u[e][2]) * wc2 + silu(u[e][3]) * wc3;
    #pragma unroll
    for (int msk = 1; msk < 32; msk <<= 1) {
        #pragma unroll
        for (int e = 0; e < 8; ++e) p[e] += __shfl_xor(p[e], msk);
    }
    #pragma unroll
    for (int e = 0; e < 8; ++e) {
        if (v[e]) { cax += p[e] * rx[e]; cay += p[e] * ry[e]; caz += p[e] * rz[e]; }
    }

    aggs[w][sub][q4 + 0] = agg0; aggs[w][sub][q4 + 1] = agg1;
    aggs[w][sub][q4 + 2] = agg2; aggs[w][sub][q4 + 3] = agg3;
    if (l32 == 0) { caccs[w][sub][0] = cax; caccs[w][sub][1] = cay; caccs[w][sub][2] = caz; }
    __syncthreads();

    if (t < 128) {
        float s = 0.f;
        #pragma unroll
        for (int i = 0; i < 4; ++i) s += aggs[i][0][t] + aggs[i][1][t];
        agg[(size_t)row * 128 + t] = s;
    }
    if (t < 3) {
        float s = 0.f;
        #pragma unroll
        for (int i = 0; i < 4; ++i) s += caccs[i][0][t] + caccs[i][1][t];
        cout[row * 3 + t] = cin[row * 3 + t] + s;
    }
}

// ---------------------------------------------------------------------------
// Node stage: hu = MLP3(concat(h, agg)); h = LayerNorm(h + hu) * g + b
// ---------------------------------------------------------------------------
__global__ __launch_bounds__(256) void k_node(
    float* __restrict__ h, const float* __restrict__ agg,
    const float* __restrict__ w1, const float* __restrict__ b1,
    const float* __restrict__ w2, const float* __restrict__ b2,
    const float* __restrict__ w3, const float* __restrict__ b3,
    const float* __restrict__ g, const float* __restrict__ b)
{
    __shared__ float xin[256];
    __shared__ float t1[256];
    __shared__ float t2[128];
    __shared__ float rs1[4], rs2[4];
    const int n = blockIdx.x, t = threadIdx.x;
    const int w = t >> 6, lane = t & 63;

    if (t < 128) xin[t] = h[(size_t)n * 128 + t];
    else         xin[t] = agg[(size_t)n * 128 + (t - 128)];
    __syncthreads();

    float a = b1[t];
    #pragma unroll 4
    for (int k = 0; k < 256; ++k) a += xin[k] * w1[k * 256 + t];
    t1[t] = silu(a);
    __syncthreads();

    if (t < 128) {
        float a2 = b2[t];
        #pragma unroll 4
        for (int k = 0; k < 256; ++k) a2 += t1[k] * w2[k * 128 + t];
        t2[t] = silu(a2);
    }
    __syncthreads();

    float x = 0.f;
    if (t < 128) {
        float a3 = b3[t];
        #pragma unroll 4
        for (int k = 0; k < 128; ++k) a3 += t2[k] * w3[k * 128 + t];
        x = xin[t] + a3;
    }
    float s1 = x, s2 = x * x;
    #pragma unroll
    for (int m = 1; m < 64; m <<= 1) { s1 += __shfl_xor(s1, m); s2 += __shfl_xor(s2, m); }
    if (lane == 0) { rs1[w] = s1; rs2[w] = s2; }
    __syncthreads();
    const float S1 = rs1[0] + rs1[1] + rs1[2] + rs1[3];
    const float S2 = rs2[0] + rs2[1] + rs2[2] + rs2[3];
    const float mu = S1 * (1.f / 128.f);
    const float var = S2 * (1.f / 128.f) - mu * mu;
    const float inv = rsqrtf(var + 1e-5f);
    if (t < 128) h[(size_t)n * 128 + t] = (x - mu) * inv * g[t] + b[t];
}

__global__ void k_copy(const float* __restrict__ src, float* __restrict__ dst, int cnt)
{
    const int i = blockIdx.x * blockDim.x + threadIdx.x;
    if (i < cnt) dst[i] = src[i];
}

// ---------------------------------------------------------------------------
extern "C" void kernel_launch(void* const* d_in, const int* in_sizes, int n_in,
                              void* d_out, int out_size, void* d_ws, size_t ws_size,
                              hipStream_t stream)
{
    const int*   eidx  = (const int*)d_in[0];
    const float* z     = (const float*)d_in[1];
    const float* at    = (const float*)d_in[2];
    const float* c0    = (const float*)d_in[3];
    const float* li_w1 = (const float*)d_in[4];
    const float* li_b1 = (const float*)d_in[5];
    const float* li_w2 = (const float*)d_in[6];
    const float* li_b2 = (const float*)d_in[7];
    const float* li_w3 = (const float*)d_in[8];
    const float* li_b3 = (const float*)d_in[9];
    const float* ew1   = (const float*)d_in[10];
    const float* eb1   = (const float*)d_in[11];
    const float* ew2   = (const float*)d_in[12];
    const float* eb2   = (const float*)d_in[13];
    const float* ew3   = (const float*)d_in[14];
    const float* eb3   = (const float*)d_in[15];
    const float* nw1   = (const float*)d_in[16];
    const float* nb1   = (const float*)d_in[17];
    const float* nw2   = (const float*)d_in[18];
    const float* nb2   = (const float*)d_in[19];
    const float* nw3   = (const float*)d_in[20];
    const float* nb3   = (const float*)d_in[21];
    const float* cw1   = (const float*)d_in[22];
    const float* cb1   = (const float*)d_in[23];
    const float* cw2   = (const float*)d_in[24];
    const float* lng   = (const float*)d_in[25];
    const float* lnb   = (const float*)d_in[26];

    float* ws   = (float*)d_ws;
    float* h    = ws;                       // [4096,128]
    float* P    = h   + (size_t)NN * 128;   // [4096,256]
    float* Q    = P   + (size_t)NN * 256;   // [4096,256]
    float* agg  = Q   + (size_t)NN * 256;   // [4096,128]
    float* cbA  = agg + (size_t)NN * 128;   // [4096,3]
    float* cbB  = cbA + (size_t)NN * 3;     // [4096,3]
    float* outp = (float*)d_out;

    k_init_h<<<NN, 256, 0, stream>>>(z, at, li_w1, li_b1, li_w2, li_b2, li_w3, li_b3, h);
    k_copy<<<(NN * 3 + 255) / 256, 256, 0, stream>>>(c0, cbA, NN * 3);

    for (int l = 0; l < NLAYER; ++l) {
        const float* ew1l = ew1 + (size_t)l * 257 * 256;
        k_pq<<<NN, 256, 0, stream>>>(h, ew1l, eb1 + l * 256, P, Q);

        const float* cin = (l & 1) ? cbB : cbA;
        float* cout      = (l == NLAYER - 1) ? outp : ((l & 1) ? cbA : cbB);
        k_edge<<<NN, 256, 0, stream>>>(eidx, cin, cout, P, Q,
            ew1l + 256 * 256,
            ew2 + (size_t)l * 256 * 128, eb2 + l * 128,
            ew3 + (size_t)l * 128 * 128, eb3 + l * 128,
            cw1 + (size_t)l * 128 * 128, cb1 + l * 128,
            cw2 + (size_t)l * 128, agg);

        k_node<<<NN, 256, 0, stream>>>(h, agg,
            nw1 + (size_t)l * 256 * 256, nb1 + l * 256,
            nw2 + (size_t)l * 256 * 128, nb2 + l * 128,
            nw3 + (size_t)l * 128 * 128, nb3 + l * 128,
            lng + l * 128, lnb + l * 128);
    }
}

// Round 14
// 1804.086 us; speedup vs baseline: 2.5158x; 2.0650x over previous
//
#include <hip/hip_runtime.h>

#define NN   4096          // total nodes
#define EPN  63            // edges per node
#define ETOT (NN * EPN)    // 258048
#define NLAYER 6

typedef unsigned short ushort_t;
typedef unsigned int   uint_t;
typedef __attribute__((ext_vector_type(8)))  short short8;
typedef __attribute__((ext_vector_type(16))) float f32x16;

__device__ __forceinline__ float silu(float x) { return x / (1.f + __expf(-x)); }

// split fp32 -> bf16 hi (truncated; residual captured by lo) + bf16 lo (RNE)
__device__ __forceinline__ void bfsplit(float v, ushort_t& hi, ushort_t& lo) {
    uint_t u = __float_as_uint(v);
    hi = (ushort_t)(u >> 16);
    float hif = __uint_as_float(u & 0xffff0000u);
    float l = v - hif;
    uint_t ul = __float_as_uint(l);
    lo = (ushort_t)((ul + 0x7fffu + ((ul >> 16) & 1u)) >> 16);
}

// ---------------------------------------------------------------------------
// h0 = MLP3(concat(atom_types[n], z[n/64]))   : [144] -> 256 -> 128 -> 128
// ---------------------------------------------------------------------------
__global__ __launch_bounds__(256) void k_init_h(
    const float* __restrict__ z, const float* __restrict__ at,
    const float* __restrict__ w1, const float* __restrict__ b1,
    const float* __restrict__ w2, const float* __restrict__ b2,
    const float* __restrict__ w3, const float* __restrict__ b3,
    float* __restrict__ h)
{
    __shared__ float feat[144];
    __shared__ float t1[256];
    __shared__ float t2[128];
    const int n = blockIdx.x, t = threadIdx.x;
    if (t < 16)        feat[t] = at[n * 16 + t];
    else if (t < 144)  feat[t] = z[(n >> 6) * 128 + (t - 16)];
    __syncthreads();

    float a = b1[t];
    #pragma unroll 4
    for (int k = 0; k < 144; ++k) a += feat[k] * w1[k * 256 + t];
    t1[t] = silu(a);
    __syncthreads();

    if (t < 128) {
        float a2 = b2[t];
        #pragma unroll 4
        for (int k = 0; k < 256; ++k) a2 += t1[k] * w2[k * 128 + t];
        t2[t] = silu(a2);
    }
    __syncthreads();

    if (t < 128) {
        float a3 = b3[t];
        #pragma unroll 4
        for (int k = 0; k < 128; ++k) a3 += t2[k] * w3[k * 128 + t];
        h[n * 128 + t] = a3;
    }
}

// ---------------------------------------------------------------------------
// P[n][j] = eb1[j] + sum_k h[n][k]*ew1[k][j]        (j = 0..255)
// Q[n][j] =          sum_k h[n][k]*ew1[128+k][j]
// ---------------------------------------------------------------------------
__global__ __launch_bounds__(256) void k_pq(
    const float* __restrict__ h, const float* __restrict__ ew1,
    const float* __restrict__ eb1, float* __restrict__ P, float* __restrict__ Q)
{
    __shared__ float hh[128];
    const int n = blockIdx.x, j = threadIdx.x;
    if (j < 128) hh[j] = h[n * 128 + j];
    __syncthreads();
    float p = eb1[j], q = 0.f;
    #pragma unroll 4
    for (int k = 0; k < 128; ++k) {
        float hv = hh[k];
        p += hv * ew1[k * 256 + j];
        q += hv * ew1[(128 + k) * 256 + j];
    }
    P[(size_t)n * 256 + j] = p;
    Q[(size_t)n * 256 + j] = q;
}

// ---------------------------------------------------------------------------
// Pre-pack edge-MLP weights into MFMA B-fragment order, split bf16 hi/lo.
// Blob per layer (ushort): ew2hi[32768] ew2lo[32768] ew3hi[16384] ew3lo[16384]
//                          cw1hi[16384] cw1lo[16384]   (= 131072 ushorts)
// B-frag (32x32x16): n = lane&31, k = 8*(lane>>5)+j ->
//   off = ((kt*4 + ntile)*64 + lane)*8 + j,  kt = k>>4, ko = k&15,
//   lane = ((ko>>3)<<5)|(n&31), j = ko&7.
// ---------------------------------------------------------------------------
__global__ __launch_bounds__(256) void k_pack(
    const float* __restrict__ ew2, const float* __restrict__ ew3,
    const float* __restrict__ cw1, ushort_t* __restrict__ pk)
{
    const int i = blockIdx.x * 256 + threadIdx.x;
    if (i >= 6 * 65536) return;
    const int layer = i >> 16, r = i & 65535;
    ushort_t* base = pk + (size_t)layer * 131072;
    const float* src; ushort_t *dhi, *dlo; int k, nn;
    if (r < 32768)      { k = r >> 7;            nn = r & 127;
                          src = ew2 + (size_t)layer * 32768 + r;
                          dhi = base;           dlo = base + 32768; }
    else if (r < 49152) { int rr = r - 32768; k = rr >> 7; nn = rr & 127;
                          src = ew3 + (size_t)layer * 16384 + rr;
                          dhi = base + 65536;   dlo = base + 81920; }
    else                { int rr = r - 49152; k = rr >> 7; nn = rr & 127;
                          src = cw1 + (size_t)layer * 16384 + rr;
                          dhi = base + 98304;   dlo = base + 114688; }
    const int kt = k >> 4, ko = k & 15, nt = nn >> 5, col = nn & 31;
    const int lane = ((ko >> 3) << 5) | col, j = ko & 7;
    const int off = ((kt * 4 + nt) * 64 + lane) * 8 + j;
    const float x = *src;
    const uint_t u = __float_as_uint(x);
    const ushort_t hi = (ushort_t)((u + 0x7fffu + ((u >> 16) & 1u)) >> 16);
    const float hif = __uint_as_float((uint_t)hi << 16);
    const float lo = x - hif;
    const uint_t ul = __float_as_uint(lo);
    const ushort_t lo16 = (ushort_t)((ul + 0x7fffu + ((ul >> 16) & 1u)) >> 16);
    dhi[off] = hi; dlo[off] = lo16;
}

#define MFMA(A, B, C) __builtin_amdgcn_mfma_f32_32x32x16_bf16((A), (B), (C), 0, 0, 0)

// ---------------------------------------------------------------------------
// Edge stage via split-bf16 MFMA (32x32x16). One block per node.
// Waves: w -> M-tile mt=w>>1 (32 edges), N-half nh=w&1 (64 of 128 cols).
// GEMMs: t2 = silu(t1@ew2+b2), msg = t2@ew3+b3, u = msg@cw1+cb1.
// Each GEMM: acc = Ahi*Bhi + Ahi*Blo + Alo*Bhi (fp32-accurate split product).
// A-frag: row=lane&31, k=8*(lane>>5)+j (ds_read_b128 from hi/lo LDS bufs).
// C-frag: col=lane&31, row=(reg&3)+8*(reg>>2)+4*(lane>>5)  [m74/m101].
// t1/t2/msg share the hi/lo LDS buffers (phase-aliased, syncthreads-guarded).
// agg + coord segment-sums via in-register reduce (no atomics).
// ---------------------------------------------------------------------------
__global__ __launch_bounds__(256, 3) void k_edge(
    const int* __restrict__ eidx, const float* __restrict__ cin, float* __restrict__ cout,
    const float* __restrict__ P, const float* __restrict__ Q,
    const float* __restrict__ w1r,
    const ushort_t* __restrict__ pk,
    const float* __restrict__ eb2, const float* __restrict__ eb3,
    const float* __restrict__ cb1, const float* __restrict__ cw2,
    float* __restrict__ agg)
{
    __shared__ float Prow[256], w1rs[256];
    __shared__ int   ce[64];
    __shared__ float d2s[64], rxs[64], rys[64], rzs[64];
    __shared__ __align__(16) ushort_t t1hi[2][32][136];   // 17408 B
    __shared__ __align__(16) ushort_t t1lo[2][32][136];   // 17408 B
    __shared__ float aggs[4][64];
    __shared__ float caccs[4][2][3];

    const int n = blockIdx.x, t = threadIdx.x;
    const int w = t >> 6, l = t & 63, h = l >> 5, ln = l & 31;
    const int mt = w >> 1, nh = w & 1, nt0 = nh * 2;

    const int row = eidx[n * EPN];
    Prow[t] = P[(size_t)row * 256 + t];
    w1rs[t] = w1r[t];
    const int* __restrict__ colp = eidx + ETOT;
    if (t < 64) {
        const int cc = colp[n * EPN + (t < 63 ? t : 0)];
        ce[t] = cc;
        const float ex = cin[row * 3 + 0] - cin[cc * 3 + 0];
        const float ey = cin[row * 3 + 1] - cin[cc * 3 + 1];
        const float ez = cin[row * 3 + 2] - cin[cc * 3 + 2];
        rxs[t] = ex; rys[t] = ey; rzs[t] = ez;
        d2s[t] = ex * ex + ey * ey + ez * ez;
    }
    __syncthreads();

    const ushort_t* e2h = pk;
    const ushort_t* e2l = pk + 32768;
    const ushort_t* e3h = pk + 65536;
    const ushort_t* e3l = pk + 81920;
    const ushort_t* c1h = pk + 98304;
    const ushort_t* c1l = pk + 114688;

    // ---- GEMM1: t2 = silu(t1 @ ew2 + eb2), K=256 in two 128-col tiles ----
    f32x16 acc0, acc1;
    {
        const float b0 = eb2[(nt0 + 0) * 32 + ln], b1v = eb2[(nt0 + 1) * 32 + ln];
        #pragma unroll
        for (int i = 0; i < 16; ++i) { acc0[i] = b0; acc1[i] = b1v; }
    }
    const int mtf = t >> 7, colf = t & 127;

    #pragma unroll 1
    for (int tile = 0; tile < 2; ++tile) {
        const int kb = tile * 128;
        const float Pc = Prow[kb + colf], Wc = w1rs[kb + colf];
        #pragma unroll 4
        for (int e = 0; e < 32; ++e) {
            const int eg = mtf * 32 + e;
            const float q = Q[(size_t)ce[eg] * 256 + kb + colf];
            const float v = silu(Pc + q + d2s[eg] * Wc);
            ushort_t hi, lo; bfsplit(v, hi, lo);
            t1hi[mtf][e][colf] = hi; t1lo[mtf][e][colf] = lo;
        }
        __syncthreads();
        #pragma unroll
        for (int kt = 0; kt < 8; ++kt) {
            const short8 Ah = *(const short8*)&t1hi[mt][ln][kt * 16 + 8 * h];
            const short8 Al = *(const short8*)&t1lo[mt][ln][kt * 16 + 8 * h];
            const int ktg = tile * 8 + kt;
            {
                const short8 Bh = *(const short8*)(e2h + (size_t)((ktg * 4 + nt0 + 0) * 64 + l) * 8);
                const short8 Bl = *(const short8*)(e2l + (size_t)((ktg * 4 + nt0 + 0) * 64 + l) * 8);
                acc0 = MFMA(Ah, Bh, acc0); acc0 = MFMA(Ah, Bl, acc0); acc0 = MFMA(Al, Bh, acc0);
            }
            {
                const short8 Bh = *(const short8*)(e2h + (size_t)((ktg * 4 + nt0 + 1) * 64 + l) * 8);
                const short8 Bl = *(const short8*)(e2l + (size_t)((ktg * 4 + nt0 + 1) * 64 + l) * 8);
                acc1 = MFMA(Ah, Bh, acc1); acc1 = MFMA(Ah, Bl, acc1); acc1 = MFMA(Al, Bh, acc1);
            }
        }
        __syncthreads();
    }

    // ---- t2 -> LDS (silu + split), overwriting t1 ----
    #pragma unroll
    for (int r = 0; r < 16; ++r) {
        const int rowe = (r & 3) + 8 * (r >> 2) + 4 * h;
        ushort_t hi, lo;
        const float v0 = silu(acc0[r]); bfsplit(v0, hi, lo);
        t1hi[mt][rowe][(nt0 + 0) * 32 + ln] = hi; t1lo[mt][rowe][(nt0 + 0) * 32 + ln] = lo;
        const float v1 = silu(acc1[r]); bfsplit(v1, hi, lo);
        t1hi[mt][rowe][(nt0 + 1) * 32 + ln] = hi; t1lo[mt][rowe][(nt0 + 1) * 32 + ln] = lo;
    }
    __syncthreads();

    // ---- GEMM2: msg = t2 @ ew3 + eb3, K=128 ----
    f32x16 m0, m1;
    {
        const float b0 = eb3[(nt0 + 0) * 32 + ln], b1v = eb3[(nt0 + 1) * 32 + ln];
        #pragma unroll
        for (int i = 0; i < 16; ++i) { m0[i] = b0; m1[i] = b1v; }
    }
    #pragma unroll
    for (int kt = 0; kt < 8; ++kt) {
        const short8 Ah = *(const short8*)&t1hi[mt][ln][kt * 16 + 8 * h];
        const short8 Al = *(const short8*)&t1lo[mt][ln][kt * 16 + 8 * h];
        {
            const short8 Bh = *(const short8*)(e3h + (size_t)((kt * 4 + nt0 + 0) * 64 + l) * 8);
            const short8 Bl = *(const short8*)(e3l + (size_t)((kt * 4 + nt0 + 0) * 64 + l) * 8);
            m0 = MFMA(Ah, Bh, m0); m0 = MFMA(Ah, Bl, m0); m0 = MFMA(Al, Bh, m0);
        }
        {
            const short8 Bh = *(const short8*)(e3h + (size_t)((kt * 4 + nt0 + 1) * 64 + l) * 8);
            const short8 Bl = *(const short8*)(e3l + (size_t)((kt * 4 + nt0 + 1) * 64 + l) * 8);
            m1 = MFMA(Ah, Bh, m1); m1 = MFMA(Ah, Bl, m1); m1 = MFMA(Al, Bh, m1);
        }
    }

    // ---- agg partial: sum msg over this wave's valid edges ----
    {
        float s0 = 0.f, s1 = 0.f;
        #pragma unroll
        for (int r = 0; r < 16; ++r) {
            const int rowe = (r & 3) + 8 * (r >> 2) + 4 * h;
            const int eg = mt * 32 + rowe;
            if (eg != 63) { s0 += m0[r]; s1 += m1[r]; }
        }
        s0 += __shfl_xor(s0, 32); s1 += __shfl_xor(s1, 32);
        if (l < 32) { aggs[w][ln] = s0; aggs[w][32 + ln] = s1; }
    }
    __syncthreads();

    // ---- msg -> LDS (split), overwriting t2 ----
    #pragma unroll
    for (int r = 0; r < 16; ++r) {
        const int rowe = (r & 3) + 8 * (r >> 2) + 4 * h;
        ushort_t hi, lo;
        bfsplit(m0[r], hi, lo);
        t1hi[mt][rowe][(nt0 + 0) * 32 + ln] = hi; t1lo[mt][rowe][(nt0 + 0) * 32 + ln] = lo;
        bfsplit(m1[r], hi, lo);
        t1hi[mt][rowe][(nt0 + 1) * 32 + ln] = hi; t1lo[mt][rowe][(nt0 + 1) * 32 + ln] = lo;
    }
    __syncthreads();

    // ---- GEMM3: u = msg @ cw1 + cb1, K=128 ----
    f32x16 u0, u1;
    {
        const float b0 = cb1[(nt0 + 0) * 32 + ln], b1v = cb1[(nt0 + 1) * 32 + ln];
        #pragma unroll
        for (int i = 0; i < 16; ++i) { u0[i] = b0; u1[i] = b1v; }
    }
    #pragma unroll
    for (int kt = 0; kt < 8; ++kt) {
        const short8 Ah = *(const short8*)&t1hi[mt][ln][kt * 16 + 8 * h];
        const short8 Al = *(const short8*)&t1lo[mt][ln][kt * 16 + 8 * h];
        {
            const short8 Bh = *(const short8*)(c1h + (size_t)((kt * 4 + nt0 + 0) * 64 + l) * 8);
            const short8 Bl = *(const short8*)(c1l + (size_t)((kt * 4 + nt0 + 0) * 64 + l) * 8);
            u0 = MFMA(Ah, Bh, u0); u0 = MFMA(Ah, Bl, u0); u0 = MFMA(Al, Bh, u0);
        }
        {
            const short8 Bh = *(const short8*)(c1h + (size_t)((kt * 4 + nt0 + 1) * 64 + l) * 8);
            const short8 Bl = *(const short8*)(c1l + (size_t)((kt * 4 + nt0 + 1) * 64 + l) * 8);
            u1 = MFMA(Ah, Bh, u1); u1 = MFMA(Ah, Bl, u1); u1 = MFMA(Al, Bh, u1);
        }
    }

    // ---- coord weights: p_e = sum_col silu(u)*cw2[col]; coords += p*rel ----
    {
        const float wca = cw2[(nt0 + 0) * 32 + ln], wcb = cw2[(nt0 + 1) * 32 + ln];
        float pr[16];
        #pragma unroll
        for (int r = 0; r < 16; ++r) pr[r] = silu(u0[r]) * wca + silu(u1[r]) * wcb;
        #pragma unroll
        for (int r = 0; r < 16; ++r) {
            pr[r] += __shfl_xor(pr[r], 1);  pr[r] += __shfl_xor(pr[r], 2);
            pr[r] += __shfl_xor(pr[r], 4);  pr[r] += __shfl_xor(pr[r], 8);
            pr[r] += __shfl_xor(pr[r], 16);
        }
        if (ln == 0) {
            float cx = 0.f, cy = 0.f, cz = 0.f;
            #pragma unroll
            for (int r = 0; r < 16; ++r) {
                const int rowe = (r & 3) + 8 * (r >> 2) + 4 * h;
                const int eg = mt * 32 + rowe;
                if (eg != 63) { cx += pr[r] * rxs[eg]; cy += pr[r] * rys[eg]; cz += pr[r] * rzs[eg]; }
            }
            caccs[w][h][0] = cx; caccs[w][h][1] = cy; caccs[w][h][2] = cz;
        }
    }
    __syncthreads();

    if (t < 128) {
        const int c = t, nhh = c >> 6, lc = c & 63;
        agg[(size_t)row * 128 + c] = aggs[nhh][lc] + aggs[2 + nhh][lc];
    }
    if (t < 3) {
        float s = 0.f;
        #pragma unroll
        for (int i = 0; i < 4; ++i) s += caccs[i][0][t] + caccs[i][1][t];
        cout[row * 3 + t] = cin[row * 3 + t] + s;
    }
}

// ---------------------------------------------------------------------------
// Node stage: hu = MLP3(concat(h, agg)); h = LayerNorm(h + hu) * g + b
// ---------------------------------------------------------------------------
__global__ __launch_bounds__(256) void k_node(
    float* __restrict__ h, const float* __restrict__ agg,
    const float* __restrict__ w1, const float* __restrict__ b1,
    const float* __restrict__ w2, const float* __restrict__ b2,
    const float* __restrict__ w3, const float* __restrict__ b3,
    const float* __restrict__ g, const float* __restrict__ b)
{
    __shared__ float xin[256];
    __shared__ float t1[256];
    __shared__ float t2[128];
    __shared__ float rs1[4], rs2[4];
    const int n = blockIdx.x, t = threadIdx.x;
    const int w = t >> 6, lane = t & 63;

    if (t < 128) xin[t] = h[(size_t)n * 128 + t];
    else         xin[t] = agg[(size_t)n * 128 + (t - 128)];
    __syncthreads();

    float a = b1[t];
    #pragma unroll 4
    for (int k = 0; k < 256; ++k) a += xin[k] * w1[k * 256 + t];
    t1[t] = silu(a);
    __syncthreads();

    if (t < 128) {
        float a2 = b2[t];
        #pragma unroll 4
        for (int k = 0; k < 256; ++k) a2 += t1[k] * w2[k * 128 + t];
        t2[t] = silu(a2);
    }
    __syncthreads();

    float x = 0.f;
    if (t < 128) {
        float a3 = b3[t];
        #pragma unroll 4
        for (int k = 0; k < 128; ++k) a3 += t2[k] * w3[k * 128 + t];
        x = xin[t] + a3;
    }
    float s1 = x, s2 = x * x;
    #pragma unroll
    for (int m = 1; m < 64; m <<= 1) { s1 += __shfl_xor(s1, m); s2 += __shfl_xor(s2, m); }
    if (lane == 0) { rs1[w] = s1; rs2[w] = s2; }
    __syncthreads();
    const float S1 = rs1[0] + rs1[1] + rs1[2] + rs1[3];
    const float S2 = rs2[0] + rs2[1] + rs2[2] + rs2[3];
    const float mu = S1 * (1.f / 128.f);
    const float var = S2 * (1.f / 128.f) - mu * mu;
    const float inv = rsqrtf(var + 1e-5f);
    if (t < 128) h[(size_t)n * 128 + t] = (x - mu) * inv * g[t] + b[t];
}

__global__ void k_copy(const float* __restrict__ src, float* __restrict__ dst, int cnt)
{
    const int i = blockIdx.x * blockDim.x + threadIdx.x;
    if (i < cnt) dst[i] = src[i];
}

// ---------------------------------------------------------------------------
extern "C" void kernel_launch(void* const* d_in, const int* in_sizes, int n_in,
                              void* d_out, int out_size, void* d_ws, size_t ws_size,
                              hipStream_t stream)
{
    const int*   eidx  = (const int*)d_in[0];
    const float* z     = (const float*)d_in[1];
    const float* at    = (const float*)d_in[2];
    const float* c0    = (const float*)d_in[3];
    const float* li_w1 = (const float*)d_in[4];
    const float* li_b1 = (const float*)d_in[5];
    const float* li_w2 = (const float*)d_in[6];
    const float* li_b2 = (const float*)d_in[7];
    const float* li_w3 = (const float*)d_in[8];
    const float* li_b3 = (const float*)d_in[9];
    const float* ew1   = (const float*)d_in[10];
    const float* eb1   = (const float*)d_in[11];
    const float* ew2   = (const float*)d_in[12];
    const float* eb2   = (const float*)d_in[13];
    const float* ew3   = (const float*)d_in[14];
    const float* eb3   = (const float*)d_in[15];
    const float* nw1   = (const float*)d_in[16];
    const float* nb1   = (const float*)d_in[17];
    const float* nw2   = (const float*)d_in[18];
    const float* nb2   = (const float*)d_in[19];
    const float* nw3   = (const float*)d_in[20];
    const float* nb3   = (const float*)d_in[21];
    const float* cw1   = (const float*)d_in[22];
    const float* cb1   = (const float*)d_in[23];
    const float* cw2   = (const float*)d_in[24];
    const float* lng   = (const float*)d_in[25];
    const float* lnb   = (const float*)d_in[26];

    float* ws   = (float*)d_ws;
    float* h    = ws;                       // [4096,128]
    float* P    = h   + (size_t)NN * 128;   // [4096,256]
    float* Q    = P   + (size_t)NN * 256;   // [4096,256]
    float* agg  = Q   + (size_t)NN * 256;   // [4096,128]
    float* cbA  = agg + (size_t)NN * 128;   // [4096,3]
    float* cbB  = cbA + (size_t)NN * 3;     // [4096,3]
    ushort_t* wpk = (ushort_t*)(cbB + (size_t)NN * 3);  // 6*131072 ushorts (16B-aligned: offset 3170304 floats)
    float* outp = (float*)d_out;

    k_init_h<<<NN, 256, 0, stream>>>(z, at, li_w1, li_b1, li_w2, li_b2, li_w3, li_b3, h);
    k_copy<<<(NN * 3 + 255) / 256, 256, 0, stream>>>(c0, cbA, NN * 3);
    k_pack<<<(6 * 65536 + 255) / 256, 256, 0, stream>>>(ew2, ew3, cw1, wpk);

    for (int l = 0; l < NLAYER; ++l) {
        const float* ew1l = ew1 + (size_t)l * 257 * 256;
        k_pq<<<NN, 256, 0, stream>>>(h, ew1l, eb1 + l * 256, P, Q);

        const float* cin = (l & 1) ? cbB : cbA;
        float* cout      = (l == NLAYER - 1) ? outp : ((l & 1) ? cbA : cbB);
        k_edge<<<NN, 256, 0, stream>>>(eidx, cin, cout, P, Q,
            ew1l + 256 * 256,
            wpk + (size_t)l * 131072,
            eb2 + l * 128, eb3 + l * 128,
            cb1 + l * 128, cw2 + l * 128, agg);

        k_node<<<NN, 256, 0, stream>>>(h, agg,
            nw1 + (size_t)l * 256 * 256, nb1 + l * 256,
            nw2 + (size_t)l * 256 * 128, nb2 + l * 128,
            nw3 + (size_t)l * 128 * 128, nb3 + l * 128,
            lng + l * 128, lnb + l * 128);
    }
}